// Round 9
// baseline (136.978 us; speedup 1.0000x reference)
//
#include <hip/hip_runtime.h>

#define EPS 1e-5f

typedef float v2f __attribute__((ext_vector_type(2)));
typedef _Float16 h2 __attribute__((ext_vector_type(2)));
typedef _Float16 h4 __attribute__((ext_vector_type(4)));

constexpr int B = 32;
constexpr int H = 512;
constexpr int W = 512;
constexpr int NPIX = H * W;          // 262144
constexpr int P = 13;
constexpr int HP = H - P + 1;        // 500
constexpr int WP = W - P + 1;        // 500
constexpr int TILES_X = 4;           // 128 output cols per tile, 2 per lane
constexpr int BAND_OUT = 40;         // output rows per band
constexpr int BANDS_Y = 13;          // 0..11 -> rows 0..479; band 12 (y0=460) -> 480..499
constexpr int G = 13;                // rows per staged group == ring depth
constexpr int NGROUPS = 4;           // 52 input rows; 460+52=512 -> no row clamp
constexpr int ITER_LAST_EMIT = 32;   // band 12 emits t>=32 -> rows 480..499
constexpr int BLOCKS_PER_B = TILES_X * BANDS_Y;  // 52
constexpr int RSH = 144;             // LDS row stride in f16 (140 used; 18 lanes x 8 f16 DMA)

// direct global->LDS DMA, 16 B per active lane, dst = uniform base + lane*16
#define GLOAD_LDS16(gp, lp)                                                    \
  __builtin_amdgcn_global_load_lds(                                            \
      (const __attribute__((address_space(1))) unsigned int*)(const void*)(gp),\
      (__attribute__((address_space(3))) unsigned int*)(void*)(lp), 16, 0, 0)

// ---------------------------------------------------------------------------
// Pre-pass: f32 -> f16 planar conversion (for DMA-stageable half-size LDS
// tiles) + EXACT f32 global moments (moved out of the patch kernel).
// grid = 32*32 = 1024 blocks x 256 thr; 96 MB HBM streaming.
// ---------------------------------------------------------------------------
__global__ __launch_bounds__(256) void prepass_kernel(
    const float* __restrict__ x1, const float* __restrict__ x2,
    _Float16* __restrict__ p1, _Float16* __restrict__ p2,
    float* __restrict__ gs) {
  int b = blockIdx.x >> 5;
  int chunk = blockIdx.x & 31;
  int tid = threadIdx.x;
  size_t base4 = (size_t)b * (NPIX / 4) + (size_t)chunk * 2048;
  const float4* q1 = (const float4*)x1 + base4;
  const float4* q2 = (const float4*)x2 + base4;
  h4* o1 = (h4*)p1 + base4;
  h4* o2 = (h4*)p2 + base4;

  float s1 = 0.f, s2 = 0.f, s11 = 0.f, s22 = 0.f, s12 = 0.f;
#pragma unroll
  for (int i = 0; i < 8; ++i) {
    float4 a = q1[i * 256 + tid];
    float4 c = q2[i * 256 + tid];
    s1 += a.x + a.y + a.z + a.w;
    s2 += c.x + c.y + c.z + c.w;
    s11 = fmaf(a.x, a.x, fmaf(a.y, a.y, fmaf(a.z, a.z, fmaf(a.w, a.w, s11))));
    s22 = fmaf(c.x, c.x, fmaf(c.y, c.y, fmaf(c.z, c.z, fmaf(c.w, c.w, s22))));
    s12 = fmaf(a.x, c.x, fmaf(a.y, c.y, fmaf(a.z, c.z, fmaf(a.w, c.w, s12))));
    h4 ha = {(_Float16)a.x, (_Float16)a.y, (_Float16)a.z, (_Float16)a.w};
    h4 hc = {(_Float16)c.x, (_Float16)c.y, (_Float16)c.z, (_Float16)c.w};
    o1[i * 256 + tid] = ha;
    o2[i * 256 + tid] = hc;
  }

  float v[5] = {s1, s2, s11, s22, s12};
  __shared__ float red[5][4];
#pragma unroll
  for (int k = 0; k < 5; ++k)
#pragma unroll
    for (int off = 32; off > 0; off >>= 1) v[k] += __shfl_down(v[k], off, 64);
  int lane = tid & 63, wave = tid >> 6;
  if (lane == 0)
#pragma unroll
    for (int k = 0; k < 5; ++k) red[k][wave] = v[k];
  __syncthreads();
  if (tid == 0)
#pragma unroll
    for (int k = 0; k < 5; ++k)
      atomicAdd(&gs[k * B + b], red[k][0] + red[k][1] + red[k][2] + red[k][3]);
}

// ---------------------------------------------------------------------------
// Patch kernel: R7 structure (async DMA double-buffer, 2 cols/lane, aligned
// taps, register ring) but staged from f16 planes:
//  - LDS tile 29.2 KB -> 15.0 KB => resident 8 waves/CU (VGPR-capped) vs 5
//    (R7 post-mortem: latency-bound at 1.25 waves/SIMD; LDS size was the cap)
//  - taps: 7 ds_read_b32/plane (4B-aligned h2), cvt to f32, math unchanged
//  - global moments moved to prepass (exact f32; fewer instr/step here)
// grid = 32*4*13 = 1664 single-wave blocks.
// ---------------------------------------------------------------------------
__global__ __launch_bounds__(64) void ncc_fused_kernel(
    const _Float16* __restrict__ p1, const _Float16* __restrict__ p2,
    float* __restrict__ part) {
  const int bid = blockIdx.x;
  const int b    = bid / BLOCKS_PER_B;
  const int rem  = bid % BLOCKS_PER_B;
  const int tile = rem % TILES_X;
  const int band = rem / TILES_X;
  const bool last = (band == BANDS_Y - 1);
  const int x0 = tile * 128;
  const int y0 = last ? (HP - BAND_OUT) : band * BAND_OUT;  // 460 for last band
  const int tid = threadIdx.x;
  const int c0 = x0 + 2 * tid;
  const bool valid0 = c0 < WP;
  const bool valid1 = (c0 + 1) < WP;

  __shared__ _Float16 sa[2][G][RSH];   // 7488 B
  __shared__ _Float16 sb[2][G][RSH];   // 7488 B

  const _Float16* r1 = p1 + (size_t)b * NPIX + (size_t)y0 * W + x0;
  const _Float16* r2 = p2 + (size_t)b * NPIX + (size_t)y0 * W + x0;

  // loader: 18 lanes x 8 f16 (16 B) = 144 f16/row/plane. Tile 3 clamp: lanes
  // 16,17 re-read cols 504..511 into slots 128..143, consumed only by
  // out-cols >= 500 (masked by valid*).
  int qoff = tid * 8;
  { int mx = W - x0 - 8; if (qoff > mx) qoff = mx; }
  const bool loader = tid < 18;

  auto stage = [&](int g, int buf) {
    if (loader) {
#pragma unroll
      for (int r = 0; r < G; ++r) {
        GLOAD_LDS16(r1 + (size_t)(g * G + r) * W + qoff, &sa[buf][r][0]);
        GLOAD_LDS16(r2 + (size_t)(g * G + r) * W + qoff, &sb[buf][r][0]);
      }
    }
  };

  // vertical ring in registers, v2f across the lane's 2 cols (slot = u)
  v2f rr1[G], rr2[G], rr11[G], rr22[G], rr12[G];
  v2f S1 = {0.f, 0.f}, S2 = {0.f, 0.f}, S11 = {0.f, 0.f}, S22 = {0.f, 0.f},
      S12 = {0.f, 0.f};
  float acc = 0.f;
  const float inv_n = 1.0f / 169.0f;

  auto step = [&](int u, int buf, int t, bool fill) {
    const h2* pa = (const h2*)&sa[buf][u][0];
    const h2* pb = (const h2*)&sb[buf][u][0];
    v2f A[7], Bv[7];
#pragma unroll
    for (int k = 0; k < 7; ++k) {
      h2 xa = pa[tid + k];             // 4B-aligned ds_read_b32
      h2 xb = pb[tid + k];
      A[k].x = (float)xa.x;  A[k].y = (float)xa.y;
      Bv[k].x = (float)xb.x; Bv[k].y = (float)xb.y;
    }

    // c0 window = taps 0..12; c1 window = taps 1..13 (A[6].y)
    v2f q11 = A[0] * A[0], q22 = Bv[0] * Bv[0], q12 = A[0] * Bv[0];
    v2f h1v = A[0], h2v = Bv[0], h11v = q11, h22v = q22, h12v = q12;
#pragma unroll
    for (int k = 1; k < 6; ++k) {
      h1v += A[k];
      h2v += Bv[k];
      h11v += A[k] * A[k];
      h22v += Bv[k] * Bv[k];
      h12v += A[k] * Bv[k];
    }
    float a12 = A[6].x, b12 = Bv[6].x, a13 = A[6].y, b13 = Bv[6].y;
    float h1_0 = h1v.x + h1v.y + a12;
    float h2_0 = h2v.x + h2v.y + b12;
    float h11_0 = fmaf(a12, a12, h11v.x + h11v.y);
    float h22_0 = fmaf(b12, b12, h22v.x + h22v.y);
    float h12_0 = fmaf(a12, b12, h12v.x + h12v.y);
    // incremental shift for c1
    v2f h1 = {h1_0, h1_0 - A[0].x + a13};
    v2f h2 = {h2_0, h2_0 - Bv[0].x + b13};
    v2f h11 = {h11_0, fmaf(a13, a13, h11_0 - q11.x)};
    v2f h22 = {h22_0, fmaf(b13, b13, h22_0 - q22.x)};
    v2f h12 = {h12_0, fmaf(a13, b13, h12_0 - q12.x)};

    // vertical sliding sums via register ring
    if (fill) {
      S1 += h1; S2 += h2; S11 += h11; S22 += h22; S12 += h12;
    } else {
      S1 += h1 - rr1[u]; S2 += h2 - rr2[u];
      S11 += h11 - rr11[u]; S22 += h22 - rr22[u]; S12 += h12 - rr12[u];
    }
    rr1[u] = h1; rr2[u] = h2; rr11[u] = h11; rr22[u] = h22; rr12[u] = h12;

    // emit output row y0 + t - 12 (band 12 suppresses rows < 480)
    bool do_out = (t >= 12) && (!last || t >= ITER_LAST_EMIT);
    if (do_out) {
      v2f m1 = S1 * inv_n, m2 = S2 * inv_n;
      v2f vv1 = S11 * inv_n - m1 * m1 + EPS;
      v2f vv2 = S22 * inv_n - m2 * m2 + EPS;
      v2f cross = S12 - (S1 * inv_n) * S2;
      v2f den = vv1 * vv2;
      float cc0 = cross.x * rsqrtf(den.x);
      float cc1 = cross.y * rsqrtf(den.y);
      acc += (valid0 ? cc0 : 0.f) + (valid1 ? cc1 : 0.f);
    }
  };

  // prologue: stage group 0, drain, launch async prefetch of group 1
  stage(0, 0);
  __syncthreads();            // drains DMA(0) — only exposed load latency
  stage(1, 1);                // in flight during fill compute

#pragma unroll
  for (int u = 0; u < G; ++u) step(u, 0, u, true);
  __syncthreads();            // drains DMA(1), long since landed

#pragma clang loop unroll(disable)
  for (int g = 1; g < NGROUPS; ++g) {
    if (g + 1 < NGROUPS) stage(g + 1, (g + 1) & 1);  // async into free buffer
    const int buf = g & 1;
#pragma unroll
    for (int u = 0; u < G; ++u) step(u, buf, g * G + u, false);
    __syncthreads();          // drains prefetch issued before this group
  }

  // wave-reduce patch partial, lane 0 writes block slot
#pragma unroll
  for (int off = 32; off > 0; off >>= 1) acc += __shfl_down(acc, off, 64);
  if (tid == 0) part[bid] = acc;
}

// ---------------------------------------------------------------------------
// Combine: 32 blocks; out[b] = 0.5*global + 0.5*patch_sum/(HP*WP*169)
// ---------------------------------------------------------------------------
__global__ __launch_bounds__(64) void final_kernel(
    const float* __restrict__ part, const float* __restrict__ gs,
    float* __restrict__ out) {
  int b = blockIdx.x;
  int tid = threadIdx.x;
  float s = 0.f;
  if (tid < BLOCKS_PER_B) s = part[b * BLOCKS_PER_B + tid];
#pragma unroll
  for (int off = 32; off > 0; off >>= 1) s += __shfl_down(s, off, 64);
  if (tid == 0) {
    float Nf = (float)NPIX;
    float m1 = gs[0 * B + b] / Nf;
    float m2 = gs[1 * B + b] / Nf;
    float v1 = fmaf(-m1, m1, gs[2 * B + b] / Nf);
    float v2 = fmaf(-m2, m2, gs[3 * B + b] / Nf);
    float cross = fmaf(-Nf * m1, m2, gs[4 * B + b]);
    float g = cross * rsqrtf((v1 + EPS) * (v2 + EPS)) / Nf;
    float patch = s / ((float)HP * (float)WP * 169.0f);
    out[b] = 0.5f * g + 0.5f * patch;
  }
}

extern "C" void kernel_launch(void* const* d_in, const int* in_sizes, int n_in,
                              void* d_out, int out_size, void* d_ws, size_t ws_size,
                              hipStream_t stream) {
  const float* x1 = (const float*)d_in[0];
  const float* x2 = (const float*)d_in[1];
  float* out = (float*)d_out;
  // ws map: p1 f16 [0,16MB) | p2 f16 [16,32MB) | gs 5*B f32 | part 1664 f32
  _Float16* p1 = (_Float16*)d_ws;
  _Float16* p2 = p1 + (size_t)B * NPIX;
  float* gs = (float*)(p2 + (size_t)B * NPIX);
  float* part = gs + 5 * B;

  hipMemsetAsync(gs, 0, 5 * B * sizeof(float), stream);
  prepass_kernel<<<B * 32, 256, 0, stream>>>(x1, x2, p1, p2, gs);
  ncc_fused_kernel<<<B * BLOCKS_PER_B, 64, 0, stream>>>(p1, p2, part);
  final_kernel<<<B, 64, 0, stream>>>(part, gs, out);
}

// Round 10
// 127.067 us; speedup vs baseline: 1.0780x; 1.0780x over previous
//
#include <hip/hip_runtime.h>

#define EPS 1e-5f

typedef float v2f __attribute__((ext_vector_type(2)));
typedef _Float16 h2 __attribute__((ext_vector_type(2)));
typedef _Float16 h4 __attribute__((ext_vector_type(4)));
typedef _Float16 h8 __attribute__((ext_vector_type(8)));

constexpr int B = 32;
constexpr int H = 512;
constexpr int W = 512;
constexpr int NPIX = H * W;          // 262144
constexpr int P = 13;
constexpr int HP = H - P + 1;        // 500
constexpr int WP = W - P + 1;        // 500
constexpr int TILES_X = 4;           // 128 output cols per tile, 2 per lane
constexpr int BAND_OUT = 40;         // output rows per band
constexpr int BANDS_Y = 13;          // 0..11 -> rows 0..479; band 12 (y0=460) -> 480..499
constexpr int G = 13;                // rows per staged group == ring depth (slot compile-time)
constexpr int NGROUPS = 4;           // 52 input rows; 460+52=512 -> no row clamp
constexpr int ITER_LAST_EMIT = 32;   // band 12 emits t>=32 -> rows 480..499
constexpr int BLOCKS_PER_B = TILES_X * BANDS_Y;  // 52
constexpr int PRE_CH = 32;           // prepass chunks per batch
constexpr int RSH = 140;             // LDS row length in h2 cols (35 lanes x 16 B = 140)

// direct global->LDS DMA, 16 B per active lane, dst = uniform base + lane*16
#define GLOAD_LDS16(gp, lp)                                                    \
  __builtin_amdgcn_global_load_lds(                                            \
      (const __attribute__((address_space(1))) unsigned int*)(const void*)(gp),\
      (__attribute__((address_space(3))) unsigned int*)(void*)(lp), 16, 0, 0)

// ---------------------------------------------------------------------------
// Pre-pass: build ONE interleaved (a,b) f16 plane (h2 per col) + exact f32
// global moments as per-block partials (no atomics, no memset dispatch).
// Traffic: 64 MB read + 32 MB write — the strategy's BW floor (~16 µs).
// grid = 32*32 blocks x 256 thr.
// ---------------------------------------------------------------------------
__global__ __launch_bounds__(256) void prepass_kernel(
    const float* __restrict__ x1, const float* __restrict__ x2,
    h2* __restrict__ ih, float* __restrict__ gpart) {
  int b = blockIdx.x >> 5;
  int chunk = blockIdx.x & 31;
  int tid = threadIdx.x;
  size_t base4 = (size_t)b * (NPIX / 4) + (size_t)chunk * 2048;
  const float4* q1 = (const float4*)x1 + base4;
  const float4* q2 = (const float4*)x2 + base4;
  h8* o = (h8*)ih + base4;   // 4 cols -> 4 h2 -> one 16B store

  float s1 = 0.f, s2 = 0.f, s11 = 0.f, s22 = 0.f, s12 = 0.f;
#pragma unroll
  for (int i = 0; i < 8; ++i) {
    float4 a = q1[i * 256 + tid];
    float4 c = q2[i * 256 + tid];
    s1 += a.x + a.y + a.z + a.w;
    s2 += c.x + c.y + c.z + c.w;
    s11 = fmaf(a.x, a.x, fmaf(a.y, a.y, fmaf(a.z, a.z, fmaf(a.w, a.w, s11))));
    s22 = fmaf(c.x, c.x, fmaf(c.y, c.y, fmaf(c.z, c.z, fmaf(c.w, c.w, s22))));
    s12 = fmaf(a.x, c.x, fmaf(a.y, c.y, fmaf(a.z, c.z, fmaf(a.w, c.w, s12))));
    h8 v = {(_Float16)a.x, (_Float16)c.x, (_Float16)a.y, (_Float16)c.y,
            (_Float16)a.z, (_Float16)c.z, (_Float16)a.w, (_Float16)c.w};
    o[i * 256 + tid] = v;
  }

  float v[5] = {s1, s2, s11, s22, s12};
  __shared__ float red[5][4];
#pragma unroll
  for (int k = 0; k < 5; ++k)
#pragma unroll
    for (int off = 32; off > 0; off >>= 1) v[k] += __shfl_down(v[k], off, 64);
  int lane = tid & 63, wave = tid >> 6;
  if (lane == 0)
#pragma unroll
    for (int k = 0; k < 5; ++k) red[k][wave] = v[k];
  __syncthreads();
  if (tid < 5)
    gpart[(size_t)blockIdx.x * 5 + tid] =
        red[tid][0] + red[tid][1] + red[tid][2] + red[tid][3];
}

// ---------------------------------------------------------------------------
// Patch kernel: R7's verified 2-col structure fed from the interleaved f16
// plane.
//  - LDS tile 29.2 KB (R7 f32) -> 14.6 KB: residency cap moves to VGPR
//    (2 waves/SIMD = 8 waves/CU vs R7's 5) — occupancy is THE lever
//    (VALU demand/CU ~115k cyc => 12 µs saturation floor).
//  - staging: ONE DMA stream (13/group, 35 lanes x 16 B = 140 cols both
//    images); taps: 7 ds_read_b64/step, 8 B lane stride = 2-way = free.
//  - 28 v_cvt_f32_f16 per step, then R7's f32 window math unchanged.
//  - global moments handled exactly in prepass (f32), not here.
// grid = 32*4*13 = 1664 single-wave blocks.
// ---------------------------------------------------------------------------
__global__ __launch_bounds__(64) void ncc_fused_kernel(
    const h2* __restrict__ ih, float* __restrict__ ppart) {
  const int bid = blockIdx.x;
  const int b    = bid / BLOCKS_PER_B;
  const int rem  = bid % BLOCKS_PER_B;
  const int tile = rem % TILES_X;
  const int band = rem / TILES_X;
  const bool last = (band == BANDS_Y - 1);
  const int x0 = tile * 128;
  const int y0 = last ? (HP - BAND_OUT) : band * BAND_OUT;  // 460 for last band
  const int tid = threadIdx.x;
  const int c0 = x0 + 2 * tid;
  const bool valid0 = c0 < WP;
  const bool valid1 = (c0 + 1) < WP;

  __shared__ h2 st[2][G][RSH];   // 2 x 13 x 140 x 4 B = 14560 B

  const h2* rbase = ih + (size_t)b * NPIX + (size_t)y0 * W + x0;

  // loader: 35 lanes x 16 B (4 h2 cols each) = cols x0..x0+139. Tile 3 clamp:
  // lanes whose 4-col span passes col 511 re-read cols 508..511; their LDS
  // slots feed only out-cols >= 500 (masked by valid*). DMA dst = uniform
  // base + lane*16.
  int qoff = tid * 4;                       // h2-element offset within row
  { int mx = W - x0 - 4; if (qoff > mx) qoff = mx; }
  const bool loader = tid < 35;

  auto stage = [&](int g, int buf) {
    if (loader) {
#pragma unroll
      for (int r = 0; r < G; ++r)
        GLOAD_LDS16(rbase + (size_t)(g * G + r) * W + qoff, &st[buf][r][0]);
    }
  };

  // vertical ring in registers, v2f across the lane's 2 cols (slot = u)
  v2f rr1[G], rr2[G], rr11[G], rr22[G], rr12[G];
  v2f S1 = {0.f, 0.f}, S2 = {0.f, 0.f}, S11 = {0.f, 0.f}, S22 = {0.f, 0.f},
      S12 = {0.f, 0.f};
  float acc = 0.f;
  const float inv_n = 1.0f / 169.0f;

  auto step = [&](int u, int buf, int t, bool fill) {
    const h2* row = &st[buf][u][0];
    v2f A[7], Bv[7];
#pragma unroll
    for (int k = 0; k < 7; ++k) {
      h4 q = *(const h4*)(row + 2 * tid + 2 * k);  // (a0,b0,a1,b1), 8B aligned
      A[k].x = (float)q.x;  A[k].y = (float)q.z;
      Bv[k].x = (float)q.y; Bv[k].y = (float)q.w;
    }

    // c0 window = taps 0..12; c1 window = taps 1..13 (A[6].y)
    v2f q11 = A[0] * A[0], q22 = Bv[0] * Bv[0], q12 = A[0] * Bv[0];
    v2f h1v = A[0], h2v = Bv[0], h11v = q11, h22v = q22, h12v = q12;
#pragma unroll
    for (int k = 1; k < 6; ++k) {
      h1v += A[k];
      h2v += Bv[k];
      h11v += A[k] * A[k];
      h22v += Bv[k] * Bv[k];
      h12v += A[k] * Bv[k];
    }
    float a12 = A[6].x, b12 = Bv[6].x, a13 = A[6].y, b13 = Bv[6].y;
    float h1_0 = h1v.x + h1v.y + a12;
    float h2_0 = h2v.x + h2v.y + b12;
    float h11_0 = fmaf(a12, a12, h11v.x + h11v.y);
    float h22_0 = fmaf(b12, b12, h22v.x + h22v.y);
    float h12_0 = fmaf(a12, b12, h12v.x + h12v.y);
    // incremental shift for c1
    v2f h1 = {h1_0, h1_0 - A[0].x + a13};
    v2f h2 = {h2_0, h2_0 - Bv[0].x + b13};
    v2f h11 = {h11_0, fmaf(a13, a13, h11_0 - q11.x)};
    v2f h22 = {h22_0, fmaf(b13, b13, h22_0 - q22.x)};
    v2f h12 = {h12_0, fmaf(a13, b13, h12_0 - q12.x)};

    // vertical sliding sums via register ring
    if (fill) {
      S1 += h1; S2 += h2; S11 += h11; S22 += h22; S12 += h12;
    } else {
      S1 += h1 - rr1[u]; S2 += h2 - rr2[u];
      S11 += h11 - rr11[u]; S22 += h22 - rr22[u]; S12 += h12 - rr12[u];
    }
    rr1[u] = h1; rr2[u] = h2; rr11[u] = h11; rr22[u] = h22; rr12[u] = h12;

    // emit output row y0 + t - 12 (band 12 suppresses rows < 480)
    bool do_out = (t >= 12) && (!last || t >= ITER_LAST_EMIT);
    if (do_out) {
      v2f m1 = S1 * inv_n, m2 = S2 * inv_n;
      v2f vv1 = S11 * inv_n - m1 * m1 + EPS;
      v2f vv2 = S22 * inv_n - m2 * m2 + EPS;
      v2f cross = S12 - (S1 * inv_n) * S2;
      v2f den = vv1 * vv2;
      float cc0 = cross.x * rsqrtf(den.x);
      float cc1 = cross.y * rsqrtf(den.y);
      acc += (valid0 ? cc0 : 0.f) + (valid1 ? cc1 : 0.f);
    }
  };

  // prologue: stage group 0, drain, launch async prefetch of group 1
  stage(0, 0);
  __syncthreads();            // drains DMA(0) — only exposed load latency
  stage(1, 1);                // in flight during fill compute

#pragma unroll
  for (int u = 0; u < G; ++u) step(u, 0, u, true);
  __syncthreads();            // drains DMA(1), long since landed

#pragma clang loop unroll(disable)
  for (int g = 1; g < NGROUPS; ++g) {
    if (g + 1 < NGROUPS) stage(g + 1, (g + 1) & 1);  // async into free buffer
    const int buf = g & 1;
#pragma unroll
    for (int u = 0; u < G; ++u) step(u, buf, g * G + u, false);
    __syncthreads();          // drains prefetch issued before this group
  }

  // wave-reduce patch partial, lane 0 writes block slot
#pragma unroll
  for (int off = 32; off > 0; off >>= 1) acc += __shfl_down(acc, off, 64);
  if (tid == 0) ppart[bid] = acc;
}

// ---------------------------------------------------------------------------
// Combine: 32 blocks. Reduce 52 patch partials + 32x5 global partials.
// out[b] = 0.5*global_ncc + 0.5*patch_sum/(HP*WP*169)
// ---------------------------------------------------------------------------
__global__ __launch_bounds__(64) void final_kernel(
    const float* __restrict__ ppart, const float* __restrict__ gpart,
    float* __restrict__ out) {
  int b = blockIdx.x;
  int tid = threadIdx.x;
  float s = (tid < BLOCKS_PER_B) ? ppart[b * BLOCKS_PER_B + tid] : 0.f;
  float gm[5] = {0.f, 0.f, 0.f, 0.f, 0.f};
  if (tid < PRE_CH) {
    const float* p = gpart + (size_t)(b * PRE_CH + tid) * 5;
#pragma unroll
    for (int k = 0; k < 5; ++k) gm[k] = p[k];
  }
#pragma unroll
  for (int off = 32; off > 0; off >>= 1) {
    s += __shfl_down(s, off, 64);
#pragma unroll
    for (int k = 0; k < 5; ++k) gm[k] += __shfl_down(gm[k], off, 64);
  }
  if (tid == 0) {
    float Nf = (float)NPIX;
    float m1 = gm[0] / Nf;
    float m2 = gm[1] / Nf;
    float v1 = fmaf(-m1, m1, gm[2] / Nf);
    float v2 = fmaf(-m2, m2, gm[3] / Nf);
    float cross = fmaf(-Nf * m1, m2, gm[4]);
    float g = cross * rsqrtf((v1 + EPS) * (v2 + EPS)) / Nf;
    float patch = s / ((float)HP * (float)WP * 169.0f);
    out[b] = 0.5f * g + 0.5f * patch;
  }
}

extern "C" void kernel_launch(void* const* d_in, const int* in_sizes, int n_in,
                              void* d_out, int out_size, void* d_ws, size_t ws_size,
                              hipStream_t stream) {
  const float* x1 = (const float*)d_in[0];
  const float* x2 = (const float*)d_in[1];
  float* out = (float*)d_out;
  // ws map: ih (interleaved h2) [0, 32MB) | gpart 1024*5 f32 | ppart 1664 f32
  h2* ih = (h2*)d_ws;
  float* gpart = (float*)((char*)d_ws + (size_t)B * NPIX * sizeof(h2));
  float* ppart = gpart + (size_t)B * PRE_CH * 5;

  prepass_kernel<<<B * PRE_CH, 256, 0, stream>>>(x1, x2, ih, gpart);
  ncc_fused_kernel<<<B * BLOCKS_PER_B, 64, 0, stream>>>(ih, ppart);
  final_kernel<<<B, 64, 0, stream>>>(ppart, gpart, out);
}